// Round 4
// baseline (265.699 us; speedup 1.0000x reference)
//
#include <hip/hip_runtime.h>

// Chambolle-Pock anisotropic TV prox. B=8, H=W=256, 200 iters, fp32.
//
// Round 19 (session r2/r3): wave-count reduction at CONSTANT region.
// r1 falsified block-TLP: cost model c_iter = 0.61us + 0.0325us*W
// (W = waves/CU) held for both 10w and 14w configs -> cost is linear in
// wave count, not hidden by co-resident blocks. So: fatten patch 2x4 ->
// 2x8 px/thread. Region 56x88, grid 256, T=40/H=12, 5 launches all
// UNCHANGED (error math untouched); threads 616 -> 308 (5 waves).
// DS ops/CU/iter: 80 -> 60 wave-instrs. VALU total unchanged.
// Discriminating experiment: per-wave-overhead hypothesis -> ~175us;
// VALU-throughput hypothesis -> neutral (accepting (2,1,1,1) SIMD
// imbalance, critical SIMD 2 fat waves).
// r3: fixed #pragma-after-brace compile error (directives need own line).
// Carried: ubar-only fp32 LDS dbuf, register ghosts, AoS fp16 state,
// med3 clamp (bounds all garbage reads), XCD-quad swizzle, dead-tail
// skip. Interior cols [12,76) not 8-aligned -> per-record store masks
// mA/mB. Boundary semantics (r3/r6-verified): OOB loads -> 0 -> p,q
// clamp to 0; explicitly zero SHIFTED clamp bounds at pads.

#define Hc 256
#define Wc 256
#define Bc 8
#define NPIX (Bc * Hc * Wc)          // 524288

typedef _Float16 half8_ __attribute__((ext_vector_type(8)));
typedef _Float16 half4_ __attribute__((ext_vector_type(4)));

constexpr int RRv(int H)   { return 32 + 2 * H; }          // region rows (56)
constexpr int RCv(int H)   { return 64 + 2 * H; }          // region cols (88)
constexpr int NCG8v(int H) { return RCv(H) / 8; }          // 8-wide col groups (11)
constexpr int NACTv(int H) { return (RRv(H) / 2) * NCG8v(H); }   // 308
constexpr int BLKv(int H)  { return (NACTv(H) + 63) / 64 * 64; } // 320
constexpr int LSTRv(int H) { return (RCv(H) + 2 + 3) / 4 * 4; }  // 92

constexpr float TAUc = 0.35355339f;
constexpr float SIGc = 0.35355339f;
constexpr float Ac_  = 1.0f / (1.0f + TAUc);
constexpr float Bq_  = TAUc * Ac_;

__device__ __forceinline__ float4 gld4(const float* p, int gi, int gj) {
    if ((unsigned)gi < (unsigned)Hc && (unsigned)gj < (unsigned)Wc)
        return *(const float4*)(p + (gi << 8) + gj);
    return make_float4(0.f, 0.f, 0.f, 0.f);
}
__device__ __forceinline__ float gld1(const float* p, int gi, int gj) {
    if ((unsigned)gi < (unsigned)Hc && (unsigned)gj < (unsigned)Wc)
        return p[(gi << 8) + gj];
    return 0.f;
}
// clamp to [-b, b] in one v_med3_f32; NaN v -> -b (finite, 0 when b==0).
__device__ __forceinline__ float clipf(float v, float b) {
    return __builtin_amdgcn_fmed3f(v, -b, b);
}

// ---- AoS state record: 16 halfs = [u0..3, ub0..3, p0..3, q0..3] per
// 4-px group. Record index: b*16384 + gi*64 + gjg (gjg = gj/4). ----
__device__ __forceinline__ void ldrec(const _Float16* S, int boff4, int gi, int gjg,
                                      float* u, float* ub, float* p, float* q) {
    if ((unsigned)gi < 256u && (unsigned)gjg < 64u) {
        const _Float16* rp = S + (size_t)(boff4 + (gi << 6) + gjg) * 16;
        const half8_ a = *(const half8_*)rp;
        const half8_ b = *(const half8_*)(rp + 8);
        #pragma unroll
        for (int e = 0; e < 4; ++e) { u[e] = a[e]; ub[e] = a[e + 4]; p[e] = b[e]; q[e] = b[e + 4]; }
    } else {
        #pragma unroll
        for (int e = 0; e < 4; ++e) { u[e] = 0.f; ub[e] = 0.f; p[e] = 0.f; q[e] = 0.f; }
    }
}
__device__ __forceinline__ void ldpg(const _Float16* S, int boff4, int gi, int gjg, float* pg) {
    if ((unsigned)gi < 256u && (unsigned)gjg < 64u) {
        const half4_ v = *(const half4_*)(S + (size_t)(boff4 + (gi << 6) + gjg) * 16 + 8);
        #pragma unroll
        for (int e = 0; e < 4; ++e) pg[e] = v[e];
    } else {
        #pragma unroll
        for (int e = 0; e < 4; ++e) pg[e] = 0.f;
    }
}
__device__ __forceinline__ float ldqg(const _Float16* S, int boff4, int gi, int gjg) {
    if ((unsigned)gi < 256u && (unsigned)gjg < 64u)
        return (float)S[(size_t)(boff4 + (gi << 6) + gjg) * 16 + 15];
    return 0.f;
}
__device__ __forceinline__ void strec(_Float16* S, int boff4, int gi, int gjg,
                                      const float* u, const float* ub,
                                      const float* p, const float* q) {
    _Float16* rp = S + (size_t)(boff4 + (gi << 6) + gjg) * 16;
    *(half8_*)rp = half8_{(_Float16)u[0],(_Float16)u[1],(_Float16)u[2],(_Float16)u[3],
                          (_Float16)ub[0],(_Float16)ub[1],(_Float16)ub[2],(_Float16)ub[3]};
    *(half8_*)(rp + 8) = half8_{(_Float16)p[0],(_Float16)p[1],(_Float16)p[2],(_Float16)p[3],
                                (_Float16)q[0],(_Float16)q[1],(_Float16)q[2],(_Float16)q[3]};
}

template <int T, int HL, bool FIRST, bool LAST>
__global__ __launch_bounds__(BLKv(HL))
void tv_tile(const float* __restrict__ f, const float* __restrict__ lam,
             const _Float16* __restrict__ st_in, _Float16* __restrict__ st_out,
             float* __restrict__ fin_out)
{
    constexpr int RR   = RRv(HL);
    constexpr int NCG8 = NCG8v(HL);
    constexpr int NACT = NACTv(HL);
    constexpr int LSTR = LSTRv(HL);
    static_assert(RCv(HL) % 8 == 0, "region cols must be 8-divisible");

    __shared__ float s_ub[2][RR + 2][LSTR];   // region row x at [.][x+1][.]

    const int t   = threadIdx.x;
    const int blk = blockIdx.x;            // 0..255
    // XCD-quad swizzle: all 4 members of a 2x2 tile quad share blk&7 (XCD).
    const int xc  = blk & 7;
    const int s_  = blk >> 3;
    const int m_  = s_ >> 3;               // member in quad (0..3)
    const int b   = s_ & 7;                // batch
    const int ti  = ((xc >> 1) << 1) | (m_ >> 1);   // 0..7
    const int tj  = ((xc & 1) << 1) | (m_ & 1);     // 0..3
    const int gi0 = ti * 32 - HL;
    const int gj0 = tj * 64 - HL;
    const int boff  = b * (Hc * Wc);
    const int boff4 = b * (Hc * Wc / 4);

    const bool active = (NACT == BLKv(HL)) || (t < NACT);
    const int rp  = t / NCG8;
    const int cg  = t - rp * NCG8;
    const int r   = rp * 2;                // region row of top row
    const int c0  = cg * 8;
    const int gi  = gi0 + r;               // global row of top row
    const int gj  = gj0 + c0;
    const int gjg = gj >> 2;               // 4-aligned, exact (gj mult of 4)

    const float* fp_ = f + boff;
    const float* lp_ = lam + boff;

    float u0[8], u1[8], ub0[8], ub1[8], p0[8], p1[8], q0[8], q1[8];
    float bf0[8], bf1[8];
    float pg[8], qg0, qg1;                 // ghost p row (gi-1), ghost q col (gj-1)
    float bp0[8], bp1[8], bpg[8], bq0[8], bq1[8], bqg0, bqg1;

    // ---------------- load phase ----------------
    if (active) {
        float4 fa = gld4(fp_, gi, gj),     fb4 = gld4(fp_, gi, gj + 4);
        float4 fc = gld4(fp_, gi + 1, gj), fd4 = gld4(fp_, gi + 1, gj + 4);
        const float fr0[8] = {fa.x, fa.y, fa.z, fa.w, fb4.x, fb4.y, fb4.z, fb4.w};
        const float fr1[8] = {fc.x, fc.y, fc.z, fc.w, fd4.x, fd4.y, fd4.z, fd4.w};
        #pragma unroll
        for (int j = 0; j < 8; ++j) { bf0[j] = Bq_ * fr0[j]; bf1[j] = Bq_ * fr1[j]; }

        float4 a0 = gld4(lp_, gi, gj),     a1 = gld4(lp_, gi, gj + 4);
        const float a2 = gld1(lp_, gi, gj + 8);
        float4 b0 = gld4(lp_, gi + 1, gj), b1 = gld4(lp_, gi + 1, gj + 4);
        const float b2 = gld1(lp_, gi + 1, gj + 8);
        float4 c0l = gld4(lp_, gi + 2, gj), c1l = gld4(lp_, gi + 2, gj + 4);
        const float la0[9] = {a0.x, a0.y, a0.z, a0.w, a1.x, a1.y, a1.z, a1.w, a2};
        const float la1[9] = {b0.x, b0.y, b0.z, b0.w, b1.x, b1.y, b1.z, b1.w, b2};
        const float la2[8] = {c0l.x, c0l.y, c0l.z, c0l.w, c1l.x, c1l.y, c1l.z, c1l.w};
        #pragma unroll
        for (int j = 0; j < 8; ++j) {
            bpg[j] = la0[j];   bq0[j] = la0[j + 1];
            bp0[j] = la1[j];   bq1[j] = la1[j + 1];
            bp1[j] = la2[j];
        }
        bqg0 = la0[0]; bqg1 = la1[0];

        // pad fixes: p[-1,:]=0 and q[:,-1]=0 in the reference; their
        // SHIFTED bounds are in-image there -> zero explicitly.
        if (gi < 0) {
            #pragma unroll
            for (int j = 0; j < 8; ++j) bp0[j] = 0.f;
        }
        if (gi + 1 < 0) {
            #pragma unroll
            for (int j = 0; j < 8; ++j) bp1[j] = 0.f;
        }
        if (gi - 1 < 0) {
            #pragma unroll
            for (int j = 0; j < 8; ++j) bpg[j] = 0.f;
        }
        #pragma unroll
        for (int j = 0; j < 8; ++j)
            if (gj + j < 0) { bq0[j] = 0.f; bq1[j] = 0.f; }
        if (gj - 1 < 0) { bqg0 = 0.f; bqg1 = 0.f; }

        if (FIRST) {
            #pragma unroll
            for (int j = 0; j < 8; ++j) {
                u0[j] = ub0[j] = fr0[j]; u1[j] = ub1[j] = fr1[j];
                p0[j] = p1[j] = q0[j] = q1[j] = pg[j] = 0.f;
            }
            qg0 = qg1 = 0.f;
        } else {
            ldrec(st_in, boff4, gi,     gjg,     u0,     ub0,     p0,     q0);
            ldrec(st_in, boff4, gi,     gjg + 1, u0 + 4, ub0 + 4, p0 + 4, q0 + 4);
            ldrec(st_in, boff4, gi + 1, gjg,     u1,     ub1,     p1,     q1);
            ldrec(st_in, boff4, gi + 1, gjg + 1, u1 + 4, ub1 + 4, p1 + 4, q1 + 4);
            ldpg (st_in, boff4, gi - 1, gjg,     pg);
            ldpg (st_in, boff4, gi - 1, gjg + 1, pg + 4);
            qg0 = ldqg(st_in, boff4, gi,     gjg - 1);
            qg1 = ldqg(st_in, boff4, gi + 1, gjg - 1);
        }

        *(float4*)&s_ub[0][r + 1][c0]     = make_float4(ub0[0], ub0[1], ub0[2], ub0[3]);
        *(float4*)&s_ub[0][r + 1][c0 + 4] = make_float4(ub0[4], ub0[5], ub0[6], ub0[7]);
        *(float4*)&s_ub[0][r + 2][c0]     = make_float4(ub1[0], ub1[1], ub1[2], ub1[3]);
        *(float4*)&s_ub[0][r + 2][c0 + 4] = make_float4(ub1[4], ub1[5], ub1[6], ub1[7]);
    }
    __syncthreads();

    // ---------- T fused iterations, 1 barrier each (none after last) ----------
    auto iter_step = [&](int cur, bool publish) {
        const int nxt = cur ^ 1;
        if (active) {
            const float4 m0 = *(const float4*)&s_ub[cur][r][c0];
            const float4 m1 = *(const float4*)&s_ub[cur][r][c0 + 4];
            const float4 P0 = *(const float4*)&s_ub[cur][r + 3][c0];
            const float4 P1 = *(const float4*)&s_ub[cur][r + 3][c0 + 4];
            const float  ubre0 = s_ub[cur][r + 1][c0 + 8];
            const float  ubre1 = s_ub[cur][r + 2][c0 + 8];
            const float  uble0 = s_ub[cur][r + 1][c0 - 1];
            const float  uble1 = s_ub[cur][r + 2][c0 - 1];
            const float ubm1[8] = {m0.x, m0.y, m0.z, m0.w, m1.x, m1.y, m1.z, m1.w};
            const float ubp2[8] = {P0.x, P0.y, P0.z, P0.w, P1.x, P1.y, P1.z, P1.w};

            // ---- step 1: p (vertical), q (horizontal), ghosts ----
            #pragma unroll
            for (int j = 0; j < 8; ++j) {
                pg[j] = clipf(fmaf(SIGc, ub0[j] - ubm1[j], pg[j]), bpg[j]);
                p0[j] = clipf(fmaf(SIGc, ub1[j] - ub0[j], p0[j]), bp0[j]);
                p1[j] = clipf(fmaf(SIGc, ubp2[j] - ub1[j], p1[j]), bp1[j]);
            }
            qg0 = clipf(fmaf(SIGc, ub0[0] - uble0, qg0), bqg0);
            qg1 = clipf(fmaf(SIGc, ub1[0] - uble1, qg1), bqg1);
            #pragma unroll
            for (int j = 0; j < 7; ++j) {
                q0[j] = clipf(fmaf(SIGc, ub0[j + 1] - ub0[j], q0[j]), bq0[j]);
                q1[j] = clipf(fmaf(SIGc, ub1[j + 1] - ub1[j], q1[j]), bq1[j]);
            }
            q0[7] = clipf(fmaf(SIGc, ubre0 - ub0[7], q0[7]), bq0[7]);
            q1[7] = clipf(fmaf(SIGc, ubre1 - ub1[7], q1[7]), bq1[7]);

            // ---- step 2: u, ubar ----
            #pragma unroll
            for (int j = 0; j < 8; ++j) {
                const float ql0 = (j == 0) ? qg0 : q0[j - 1];
                const float ql1 = (j == 0) ? qg1 : q1[j - 1];
                float dv, un;
                dv = (pg[j] - p0[j]) + (ql0 - q0[j]);
                un = fmaf(-Bq_, dv, fmaf(Ac_, u0[j], bf0[j]));
                ub0[j] = 2.f * un - u0[j]; u0[j] = un;
                dv = (p0[j] - p1[j]) + (ql1 - q1[j]);
                un = fmaf(-Bq_, dv, fmaf(Ac_, u1[j], bf1[j]));
                ub1[j] = 2.f * un - u1[j]; u1[j] = un;
            }

            if (publish) {
                *(float4*)&s_ub[nxt][r + 1][c0]     = make_float4(ub0[0], ub0[1], ub0[2], ub0[3]);
                *(float4*)&s_ub[nxt][r + 1][c0 + 4] = make_float4(ub0[4], ub0[5], ub0[6], ub0[7]);
                *(float4*)&s_ub[nxt][r + 2][c0]     = make_float4(ub1[0], ub1[1], ub1[2], ub1[3]);
                *(float4*)&s_ub[nxt][r + 2][c0 + 4] = make_float4(ub1[4], ub1[5], ub1[6], ub1[7]);
            }
        }
        if (publish) __syncthreads();
    };

    for (int k = 0; k < T; ++k) iter_step(k & 1, k != T - 1);

    // ------- store phase (interior only; per-4-col-record masks) -------
    // interior region cols [HL, HL+64), rows [HL, HL+32)
    const bool rowin = (r >= HL) && (r < HL + 32);
    const bool mA = (c0 >= HL)     && (c0 + 4 <= HL + 64);
    const bool mB = (c0 + 4 >= HL) && (c0 + 8 <= HL + 64);
    if (active && rowin && (mA || mB)) {
        if (LAST) {
            const int idx0 = boff + (gi << 8) + gj;
            if (mA) {
                *(float4*)&fin_out[idx0]          = make_float4(u0[0], u0[1], u0[2], u0[3]);
                *(float4*)&fin_out[idx0 + Wc]     = make_float4(u1[0], u1[1], u1[2], u1[3]);
            }
            if (mB) {
                *(float4*)&fin_out[idx0 + 4]      = make_float4(u0[4], u0[5], u0[6], u0[7]);
                *(float4*)&fin_out[idx0 + Wc + 4] = make_float4(u1[4], u1[5], u1[6], u1[7]);
            }
        } else {
            if (mA) {
                strec(st_out, boff4, gi,     gjg,     u0,     ub0,     p0,     q0);
                strec(st_out, boff4, gi + 1, gjg,     u1,     ub1,     p1,     q1);
            }
            if (mB) {
                strec(st_out, boff4, gi,     gjg + 1, u0 + 4, ub0 + 4, p0 + 4, q0 + 4);
                strec(st_out, boff4, gi + 1, gjg + 1, u1 + 4, ub1 + 4, p1 + 4, q1 + 4);
            }
        }
    }
}

extern "C" void kernel_launch(void* const* d_in, const int* in_sizes, int n_in,
                              void* d_out, int out_size, void* d_ws, size_t ws_size,
                              hipStream_t stream)
{
    const float* f   = (const float*)d_in[0];
    const float* lam = (const float*)d_in[1];
    _Float16* ws = (_Float16*)d_ws;

    // two AoS record sets, each NPIX/4 records x 32 B = 4 MB
    _Float16* S[2] = { ws, ws + (size_t)NPIX * 4 };

    dim3 grid(256);

    // 5 launches of T=40, H=12 (approximate containment; see header).
    tv_tile<40, 12, true, false><<<grid, dim3(BLKv(12)), 0, stream>>>(
        f, lam, nullptr, S[0], nullptr);

    for (int l = 1; l < 4; ++l) {
        const int w = l & 1;
        tv_tile<40, 12, false, false><<<grid, dim3(BLKv(12)), 0, stream>>>(
            f, lam, S[w ^ 1], S[w], nullptr);
    }

    // launch 3 wrote S[1]; final launch reads S[1], writes u -> d_out
    tv_tile<40, 12, false, true><<<grid, dim3(BLKv(12)), 0, stream>>>(
        f, lam, S[1], nullptr, (float*)d_out);
}